// Round 8
// baseline (439.017 us; speedup 1.0000x reference)
//
#include <hip/hip_runtime.h>
#include <math.h>

#define RED_BLOCKS 256
#define RBLK 256
#define HDIM 64
#define GRID 256          // exactly 1 block per CU -> co-resident persistent kernel
#define TBLK 1024         // 16 waves/block
#define NPT 4             // nodes per thread; GRID*TBLK*NPT = 1,048,576 >= N
#define SPAN (GRID * TBLK)

typedef int   v4i __attribute__((ext_vector_type(4)));
typedef float v4f __attribute__((ext_vector_type(4)));

// ---------------- K1: per-block partial sum / sumsq (f64, deterministic) + bar reset ----
__global__ void __launch_bounds__(RBLK) k_reduce_partial(const float* __restrict__ hu, int n,
                                                         double* __restrict__ part,
                                                         int* __restrict__ bar) {
  if (blockIdx.x == 0 && threadIdx.x == 0) *bar = 0;  // reset device barrier each call
  __shared__ double ls[RBLK];
  __shared__ double lq[RBLK];
  const v4f* hu4 = (const v4f*)hu;
  const int n4 = n >> 2;
  double s = 0.0, q = 0.0;
  for (int i = blockIdx.x * RBLK + threadIdx.x; i < n4; i += RED_BLOCKS * RBLK) {
    v4f v = hu4[i];
    double a = (double)v.x, b = (double)v.y, c = (double)v.z, d = (double)v.w;
    s += a + b + c + d;
    q += a * a + b * b + c * c + d * d;
  }
  if (blockIdx.x == 0 && threadIdx.x == 0) {  // tail, fixed order -> deterministic
    for (int i = n4 << 2; i < n; ++i) {
      double v = (double)hu[i];
      s += v;
      q += v * v;
    }
  }
  ls[threadIdx.x] = s;
  lq[threadIdx.x] = q;
  __syncthreads();
  for (int off = RBLK / 2; off > 0; off >>= 1) {
    if (threadIdx.x < off) {
      ls[threadIdx.x] += ls[threadIdx.x + off];
      lq[threadIdx.x] += lq[threadIdx.x + off];
    }
    __syncthreads();
  }
  if (threadIdx.x == 0) {
    part[blockIdx.x] = ls[0];
    part[RED_BLOCKS + blockIdx.x] = lq[0];
  }
}

// ---------------- K2: fully fused GCN (persistent, manual device barrier) ----------------
__global__ void __launch_bounds__(TBLK, 4) k_gcn(
    const float* __restrict__ hu,
    const int* __restrict__ nbr,
    const float* __restrict__ Wn1,
    const float* __restrict__ Ws1,
    const float* __restrict__ B1,
    const float* __restrict__ Wn2,
    const float* __restrict__ Ws2,
    const float* __restrict__ B2,
    const double* __restrict__ part,
    float* __restrict__ snei,
    int* __restrict__ bar,
    float* __restrict__ out,
    int n) {
  __shared__ v4f w4[HDIM];     // {Wn1, Ws1, Wn2, Ws2}
  __shared__ float bb[HDIM];
  __shared__ double red_s[RED_BLOCKS];
  __shared__ double red_q[RED_BLOCKS];
  __shared__ float sstat[2];

  const int t = threadIdx.x;
  // ---- stage A: block-redundant final stats reduction ----
  if (t < RED_BLOCKS) {
    red_s[t] = part[t];
    red_q[t] = part[RED_BLOCKS + t];
  }
  if (t < HDIM) {
    v4f w;
    w.x = Wn1[t]; w.y = Ws1[t]; w.z = Wn2[t]; w.w = Ws2[t];
    w4[t] = w;
    bb[t] = B1[t];
  }
  __syncthreads();
  for (int off = RED_BLOCKS / 2; off > 0; off >>= 1) {
    if (t < off) {
      red_s[t] += red_s[t + off];
      red_q[t] += red_q[t + off];
    }
    __syncthreads();
  }
  if (t == 0) {
    double sum = red_s[0], sumsq = red_q[0];
    double mu = sum / (double)n;
    double var = (sumsq - sum * sum / (double)n) / (double)(n - 1);
    if (var < 0.0) var = 0.0;
    double sigma = sqrt(var) + 1e-8;  // unbiased std + EPS
    sstat[0] = (float)mu;
    sstat[1] = (float)(1.0 / sigma);
  }
  __syncthreads();

  const int base = blockIdx.x * TBLK + t;
  const v4i* nbr4 = (const v4i*)nbr;

  // ---- stage B: layer1 for NPT nodes/thread; nbr + sself stay in registers ----
  int u[NPT];
  bool ok[NPT];
#pragma unroll
  for (int k = 0; k < NPT; ++k) {
    int uu = base + k * SPAN;
    ok[k] = uu < n;
    u[k] = ok[k] ? uu : (n - 1);
  }
  v4i nb[NPT];
#pragma unroll
  for (int k = 0; k < NPT; ++k) nb[k] = __builtin_nontemporal_load(nbr4 + u[k]);
  float hself[NPT];
#pragma unroll
  for (int k = 0; k < NPT; ++k) hself[k] = hu[u[k]];
  float g[NPT][4];
#pragma unroll
  for (int k = 0; k < NPT; ++k) {  // 16 independent random gathers in flight
    g[k][0] = hu[nb[k].x];
    g[k][1] = hu[nb[k].y];
    g[k][2] = hu[nb[k].z];
    g[k][3] = hu[nb[k].w];
  }

  const float mu = sstat[0];
  const float inv = sstat[1];
  v4f a4, c4;
  a4.x = ((g[0][0] + g[0][1]) + (g[0][2] + g[0][3]) - 4.0f * mu) * inv;
  a4.y = ((g[1][0] + g[1][1]) + (g[1][2] + g[1][3]) - 4.0f * mu) * inv;
  a4.z = ((g[2][0] + g[2][1]) + (g[2][2] + g[2][3]) - 4.0f * mu) * inv;
  a4.w = ((g[3][0] + g[3][1]) + (g[3][2] + g[3][3]) - 4.0f * mu) * inv;
  c4.x = (hself[0] - mu) * inv;
  c4.y = (hself[1] - mu) * inv;
  c4.z = (hself[2] - mu) * inv;
  c4.w = (hself[3] - mu) * inv;

  v4f z = {0.0f, 0.0f, 0.0f, 0.0f};
  v4f sn4 = z, ss4 = z;  // lane = node k
#pragma unroll
  for (int j = 0; j < HDIM; ++j) {
    v4f w = w4[j];
    v4f tt = a4 * w.x + c4 * w.y + bb[j];
    v4f r = __builtin_elementwise_max(tt, z);
    sn4 += r * w.z;
    ss4 += r * w.w;
  }
  if (ok[0]) snei[u[0]] = sn4.x;
  if (ok[1]) snei[u[1]] = sn4.y;
  if (ok[2]) snei[u[2]] = sn4.z;
  if (ok[3]) snei[u[3]] = sn4.w;

  // ---- device-wide barrier (1 block/CU, all co-resident) ----
  __threadfence();  // device-scope release: snei visible past per-XCD L2
  __syncthreads();
  if (t == 0) {
    __hip_atomic_fetch_add(bar, 1, __ATOMIC_ACQ_REL, __HIP_MEMORY_SCOPE_AGENT);
    while (__hip_atomic_load(bar, __ATOMIC_ACQUIRE, __HIP_MEMORY_SCOPE_AGENT) < GRID) {
      __builtin_amdgcn_s_sleep(8);
    }
  }
  __syncthreads();

  // ---- stage C: layer2 gather of snei with the registered nb ----
  float acc[NPT];
#pragma unroll
  for (int k = 0; k < NPT; ++k) {
    acc[k] = (snei[nb[k].x] + snei[nb[k].y]) + (snei[nb[k].z] + snei[nb[k].w]);
  }
  const float b2v = B2[0];
#pragma unroll
  for (int k = 0; k < NPT; ++k) {
    if (ok[k]) {
      float d = b2v + acc[k] + (k == 0 ? ss4.x : k == 1 ? ss4.y : k == 2 ? ss4.z : ss4.w);
      __builtin_nontemporal_store(0.3f * tanhf(d), out + u[k]);
    }
  }
}

extern "C" void kernel_launch(void* const* d_in, const int* in_sizes, int n_in,
                              void* d_out, int out_size, void* d_ws, size_t ws_size,
                              hipStream_t stream) {
  const float* hu  = (const float*)d_in[0];
  const int*   nbr = (const int*)d_in[1];
  // d_in[2] = neighbor_offsets: fixed degree-4 CSR, not needed.
  const float* Wn1 = (const float*)d_in[3];
  const float* Ws1 = (const float*)d_in[4];
  const float* B1  = (const float*)d_in[5];
  const float* Wn2 = (const float*)d_in[6];
  const float* Ws2 = (const float*)d_in[7];
  const float* B2  = (const float*)d_in[8];
  float* out = (float*)d_out;
  const int n = in_sizes[0];

  char* ws = (char*)d_ws;
  double* part = (double*)ws;                 // 2*256*8 = 4 KiB
  int* bar     = (int*)(ws + 4096);
  float* snei  = (float*)(ws + 8192);         // n*4 B

  k_reduce_partial<<<RED_BLOCKS, RBLK, 0, stream>>>(hu, n, part, bar);
  k_gcn<<<GRID, TBLK, 0, stream>>>(hu, nbr, Wn1, Ws1, B1, Wn2, Ws2, B2,
                                   part, snei, bar, out, n);
}

// Round 9
// 61.195 us; speedup vs baseline: 7.1741x; 7.1741x over previous
//
#include <hip/hip_runtime.h>
#include <math.h>

#define RED_BLOCKS 256
#define BLK 256
#define HDIM 64
#define NPT 4                    // nodes per thread
#define BNODES (BLK * NPT)       // nodes per block

typedef int   v4i __attribute__((ext_vector_type(4)));
typedef float v4f __attribute__((ext_vector_type(4)));

// L1-bypassing gather load: agent-scope relaxed load emits sc0 (L1 not agent-coherent),
// so outstanding requests are bounded by per-wave vmcnt, not the per-CU L1 MSHR pool,
// and a 4B request doesn't drag a 64B L1 line fill.
__device__ __forceinline__ float ld_gather(const float* __restrict__ p) {
  int v = __hip_atomic_load((const int*)p, __ATOMIC_RELAXED, __HIP_MEMORY_SCOPE_AGENT);
  return __int_as_float(v);
}

// ---------------- K1: per-block partial sum / sumsq (f64, deterministic) ----------------
__global__ void __launch_bounds__(BLK) k_reduce_partial(const float* __restrict__ hu, int n,
                                                        double* __restrict__ part) {
  __shared__ double ls[BLK];
  __shared__ double lq[BLK];
  const v4f* hu4 = (const v4f*)hu;
  const int n4 = n >> 2;
  double s = 0.0, q = 0.0;
  for (int i = blockIdx.x * BLK + threadIdx.x; i < n4; i += RED_BLOCKS * BLK) {
    v4f v = hu4[i];
    double a = (double)v.x, b = (double)v.y, c = (double)v.z, d = (double)v.w;
    s += a + b + c + d;
    q += a * a + b * b + c * c + d * d;
  }
  if (blockIdx.x == 0 && threadIdx.x == 0) {  // tail, fixed order -> deterministic
    for (int i = n4 << 2; i < n; ++i) {
      double v = (double)hu[i];
      s += v;
      q += v * v;
    }
  }
  ls[threadIdx.x] = s;
  lq[threadIdx.x] = q;
  __syncthreads();
  for (int off = BLK / 2; off > 0; off >>= 1) {
    if (threadIdx.x < off) {
      ls[threadIdx.x] += ls[threadIdx.x + off];
      lq[threadIdx.x] += lq[threadIdx.x + off];
    }
    __syncthreads();
  }
  if (threadIdx.x == 0) {
    part[blockIdx.x] = ls[0];
    part[RED_BLOCKS + blockIdx.x] = lq[0];
  }
}

// ---------------- K2: block-redundant stats finalize + layer1 (L1-bypass hu gather) ----
__global__ void __launch_bounds__(BLK) k_layer1(
    const float* __restrict__ hu,
    const int* __restrict__ nbr,
    const float* __restrict__ Wn1,
    const float* __restrict__ Ws1,
    const float* __restrict__ B1,
    const float* __restrict__ Wn2,
    const float* __restrict__ Ws2,
    const double* __restrict__ part,
    float* __restrict__ snei,
    float* __restrict__ sself,
    int n) {
  __shared__ v4f w4[HDIM];     // {Wn1, Ws1, Wn2, Ws2}
  __shared__ float bb[HDIM];
  __shared__ double red_s[BLK];
  __shared__ double red_q[BLK];
  __shared__ float sstat[2];

  const int t = threadIdx.x;
  red_s[t] = part[t];
  red_q[t] = part[RED_BLOCKS + t];
  if (t < HDIM) {
    v4f w;
    w.x = Wn1[t]; w.y = Ws1[t]; w.z = Wn2[t]; w.w = Ws2[t];
    w4[t] = w;
    bb[t] = B1[t];
  }
  __syncthreads();
  for (int off = BLK / 2; off > 0; off >>= 1) {
    if (t < off) {
      red_s[t] += red_s[t + off];
      red_q[t] += red_q[t + off];
    }
    __syncthreads();
  }
  if (t == 0) {
    double sum = red_s[0], sumsq = red_q[0];
    double mu = sum / (double)n;
    double var = (sumsq - sum * sum / (double)n) / (double)(n - 1);
    if (var < 0.0) var = 0.0;
    double sigma = sqrt(var) + 1e-8;  // unbiased std + EPS
    sstat[0] = (float)mu;
    sstat[1] = (float)(1.0 / sigma);
  }
  __syncthreads();

  const int base = blockIdx.x * BNODES + t;
  const v4i* nbr4 = (const v4i*)nbr;

  int u[NPT];
  bool ok[NPT];
#pragma unroll
  for (int k = 0; k < NPT; ++k) {
    int uu = base + k * BLK;
    ok[k] = uu < n;
    u[k] = ok[k] ? uu : (n - 1);
  }
  v4i nb[NPT];
#pragma unroll
  for (int k = 0; k < NPT; ++k) nb[k] = __builtin_nontemporal_load(nbr4 + u[k]);
  float hself[NPT];
#pragma unroll
  for (int k = 0; k < NPT; ++k) hself[k] = hu[u[k]];
  // 16 independent L1-bypass random gathers in flight (vmcnt-bounded, not MSHR-bounded)
  float g[NPT][4];
#pragma unroll
  for (int k = 0; k < NPT; ++k) {
    g[k][0] = ld_gather(hu + nb[k].x);
    g[k][1] = ld_gather(hu + nb[k].y);
    g[k][2] = ld_gather(hu + nb[k].z);
    g[k][3] = ld_gather(hu + nb[k].w);
  }

  const float mu = sstat[0];
  const float inv = sstat[1];
  v4f a4, c4;
  a4.x = ((g[0][0] + g[0][1]) + (g[0][2] + g[0][3]) - 4.0f * mu) * inv;
  a4.y = ((g[1][0] + g[1][1]) + (g[1][2] + g[1][3]) - 4.0f * mu) * inv;
  a4.z = ((g[2][0] + g[2][1]) + (g[2][2] + g[2][3]) - 4.0f * mu) * inv;
  a4.w = ((g[3][0] + g[3][1]) + (g[3][2] + g[3][3]) - 4.0f * mu) * inv;
  c4.x = (hself[0] - mu) * inv;
  c4.y = (hself[1] - mu) * inv;
  c4.z = (hself[2] - mu) * inv;
  c4.w = (hself[3] - mu) * inv;

  v4f z = {0.0f, 0.0f, 0.0f, 0.0f};
  v4f sn4 = z, ss4 = z;  // lane = node k
#pragma unroll
  for (int j = 0; j < HDIM; ++j) {
    v4f w = w4[j];
    v4f tt = a4 * w.x + c4 * w.y + bb[j];
    v4f r = __builtin_elementwise_max(tt, z);
    sn4 += r * w.z;
    ss4 += r * w.w;
  }
  if (ok[0]) { snei[u[0]] = sn4.x; __builtin_nontemporal_store(ss4.x, sself + u[0]); }
  if (ok[1]) { snei[u[1]] = sn4.y; __builtin_nontemporal_store(ss4.y, sself + u[1]); }
  if (ok[2]) { snei[u[2]] = sn4.z; __builtin_nontemporal_store(ss4.z, sself + u[2]); }
  if (ok[3]) { snei[u[3]] = sn4.w; __builtin_nontemporal_store(ss4.w, sself + u[3]); }
}

// ---------------- K3: layer2 (L1-bypass snei gather) + tanh ----------------
__global__ void __launch_bounds__(BLK) k_layer2(
    const int* __restrict__ nbr,
    const float* __restrict__ snei,
    const float* __restrict__ sself,
    const float* __restrict__ B2,
    float* __restrict__ out,
    int n) {
  const int t = threadIdx.x;
  const int base = blockIdx.x * BNODES + t;
  const v4i* nbr4 = (const v4i*)nbr;

  int u[NPT];
  bool ok[NPT];
#pragma unroll
  for (int k = 0; k < NPT; ++k) {
    int uu = base + k * BLK;
    ok[k] = uu < n;
    u[k] = ok[k] ? uu : (n - 1);
  }
  v4i nb[NPT];
#pragma unroll
  for (int k = 0; k < NPT; ++k) nb[k] = __builtin_nontemporal_load(nbr4 + u[k]);
  float ss[NPT];
#pragma unroll
  for (int k = 0; k < NPT; ++k) ss[k] = __builtin_nontemporal_load(sself + u[k]);
  // 16 independent L1-bypass random gathers in flight
  float g[NPT][4];
#pragma unroll
  for (int k = 0; k < NPT; ++k) {
    g[k][0] = ld_gather(snei + nb[k].x);
    g[k][1] = ld_gather(snei + nb[k].y);
    g[k][2] = ld_gather(snei + nb[k].z);
    g[k][3] = ld_gather(snei + nb[k].w);
  }
  const float b2v = B2[0];
#pragma unroll
  for (int k = 0; k < NPT; ++k) {
    if (ok[k]) {
      float d = b2v + ((g[k][0] + g[k][1]) + (g[k][2] + g[k][3])) + ss[k];
      __builtin_nontemporal_store(0.3f * tanhf(d), out + u[k]);
    }
  }
}

extern "C" void kernel_launch(void* const* d_in, const int* in_sizes, int n_in,
                              void* d_out, int out_size, void* d_ws, size_t ws_size,
                              hipStream_t stream) {
  const float* hu  = (const float*)d_in[0];
  const int*   nbr = (const int*)d_in[1];
  // d_in[2] = neighbor_offsets: fixed degree-4 CSR, not needed.
  const float* Wn1 = (const float*)d_in[3];
  const float* Ws1 = (const float*)d_in[4];
  const float* B1  = (const float*)d_in[5];
  const float* Wn2 = (const float*)d_in[6];
  const float* Ws2 = (const float*)d_in[7];
  const float* B2  = (const float*)d_in[8];
  float* out = (float*)d_out;
  const int n = in_sizes[0];

  char* ws = (char*)d_ws;
  double* part = (double*)ws;                 // 2*256*8 = 4 KiB
  float* snei  = (float*)(ws + 8192);         // n*4 B
  float* sself = snei + n;                    // n*4 B

  k_reduce_partial<<<RED_BLOCKS, BLK, 0, stream>>>(hu, n, part);
  int blocks = (n + BNODES - 1) / BNODES;
  k_layer1<<<blocks, BLK, 0, stream>>>(hu, nbr, Wn1, Ws1, B1, Wn2, Ws2, part,
                                       snei, sself, n);
  k_layer2<<<blocks, BLK, 0, stream>>>(nbr, snei, sself, B2, out, n);
}